// Round 1
// 372.922 us; speedup vs baseline: 1.1328x; 1.1328x over previous
//
#include <hip/hip_runtime.h>

// ---------------------------------------------------------------------------
// SphericalHarmonicsShellsConv  (MI355X / gfx950) — round 5
//
// Per (b,v):  y(30x256) = K^T(30x32) · G(32x256) gathered  ->  CG recombine.
//
// NEW: GEMM moved to matrix cores. Computes D(256x32) = G^T · Kpad via
// mfma_f32_16x16x32_bf16 with split-bf16 (hi+lo) 3-MFMA emulation => fp32-
// equivalent accuracy. C/D layout (m89-verified) gives each lane 4 consecutive
// channels at one y-row => f32x4 epilogue stores + ds_write_b128.
// Y now staged in LDS as f32 (25.4 KB); CG jobs read f32x4 directly (no
// unpack). Same jobs/lists tables (element-unit offsets, unchanged).
// ---------------------------------------------------------------------------

#define NB      4
#define NN      4096
#define NV      2048
#define NP      32
#define NY      30
#define YROWS   26
#define YCOLS   244          // element row stride (240 cols + 4 pad)
#define NJOBS_CG 972
#define LISTS_OFF 13088      // 3269*4 -> 16-aligned
#define JOBS_OFF  39248      // LISTS_OFF + 3270*8

typedef float        f32x4 __attribute__((ext_vector_type(4)));
typedef unsigned int u32x4 __attribute__((ext_vector_type(4)));
typedef short        s16x8 __attribute__((ext_vector_type(8)));

// ---- term tables (34 terms) ------------------------------------------------
// cg = -1: l0 copy (j=J,l=0); cg = -2: j0 copy (j=0,l=J); else offset in cgws
__device__ const int T_J[34]  = {0,0,0,0, 1,1,1,1,1,1,1,1,1, 2,2,2,2,2,2,2,2,2,2,2, 3,3,3,3,3,3,3,3,3,3};
__device__ const int T_j[34]  = {0,1,2,3, 1,0,1,2,1,2,3,2,3, 2,0,1,2,3,1,2,3,1,2,3, 3,0,2,3,1,2,3,1,2,3};
__device__ const int T_l[34]  = {0,1,2,3, 0,1,1,1,2,2,2,3,3, 0,2,1,1,1,2,2,2,3,3,3, 0,3,1,1,2,2,2,3,3,3};
__device__ const int T_ch[34] = {0,64,112,144, 0,48,112,160,192,240,272,288,320,
                                 0,32,96,144,176,192,240,272,288,336,368,
                                 0,16,80,112,128,176,208,224,272,304};
__device__ const int T_cg[34] = {-1,0,9,34, -1,-2,83,110,155,200,275,380,485,
                                 -1,-2,632,677,752,857,932,1057,1232,1337,1512,
                                 -1,-2,1757,1862,2009,2114,2289,2534,2681,2926};

__device__ const int YOFF[4]  = {0, 4, 13, 23};
__device__ const int YOFFP[4] = {0, 0, 9, 19};    // row base in reduced Y (j>=1)
__device__ const int COFF[4]  = {0, 16, 64, 144};
__device__ const int WTAB[4]  = {160, 336, 384, 320};
__device__ const int OTAB[4]  = {0, 1310720, 9568256, 25296896};

__device__ const float FACT[11] = {1.f,1.f,2.f,6.f,24.f,120.f,720.f,5040.f,
                                   40320.f,362880.f,3628800.f};

// ---------------------------------------------------------------------------
__device__ float su2cgf(int j1, int m1, int j2, int m2, int j3, int m3) {
    int vmin = -j1 + j2 + m3;
    if (-j1 + m1 > vmin) vmin = -j1 + m1;
    if (0 > vmin) vmin = 0;
    int vmax = j2 + j3 + m1;
    if (j3 - j1 + j2 < vmax) vmax = j3 - j1 + j2;
    if (j3 + m3 < vmax) vmax = j3 + m3;
    float num = (2.f * j3 + 1.f) * FACT[j3 + j1 - j2] * FACT[j3 - j1 + j2] *
                FACT[j1 + j2 - j3] * FACT[j3 + m3] * FACT[j3 - m3];
    float den = FACT[j1 + j2 + j3 + 1] * FACT[j1 - m1] * FACT[j1 + m1] *
                FACT[j2 - m2] * FACT[j2 + m2];
    float Cc = sqrtf(num / den);
    float S = 0.f;
    for (int v = vmin; v <= vmax; ++v) {
        float t = FACT[j2 + j3 + m1 - v] * FACT[j1 - m1 + v] /
                  (FACT[v] * FACT[j3 - j1 + j2 - v] * FACT[j3 + m3 - v] *
                   FACT[v + j1 - j2 - m3]);
        S += ((v + j2 + m2) & 1) ? -t : t;
    }
    return Cc * S;
}

__device__ void qelemf(int l, int row, int col, float* pre, float* pim) {
    int m = row - l;
    const float s2 = 0.70710678118654752440f;
    float qr = 0.f, qi = 0.f;
    if (m < 0) {
        if (col == l - m) qr = s2;
        if (col == l + m) qi = -s2;
    } else if (m == 0) {
        if (col == l) qr = 1.f;
    } else {
        float sg = (m & 1) ? -1.f : 1.f;
        if (col == l + m) qr = sg * s2;
        if (col == l - m) qi = sg * s2;
    }
    float rr, ii;
    switch (l & 3) {
        case 0:  rr = qr;  ii = qi;  break;
        case 1:  rr = qi;  ii = -qr; break;
        case 2:  rr = -qr; ii = -qi; break;
        default: rr = -qi; ii = qr;  break;
    }
    *pre = rr; *pim = ii;
}

// ---------------------------------------------------------------------------
// kernel A: dense real-CG tables (27 blocks; block k = k-th cg term)
__global__ __launch_bounds__(256) void sh_cg_kernel(float* __restrict__ cgws) {
    int k = blockIdx.x;
    int t = 0, seen = -1;
    for (t = 0; t < 34; ++t) { if (T_cg[t] >= 0) { ++seen; if (seen == k) break; } }
    int j1 = T_j[t], j2 = T_l[t], j3 = T_J[t], off = T_cg[t];
    int d1 = 2 * j1 + 1, d2 = 2 * j2 + 1, d3 = 2 * j3 + 1;
    int tot = d1 * d2 * d3;
    for (int e = threadIdx.x; e < tot; e += blockDim.x) {
        int a  = e / (d2 * d3);
        int b2 = (e / d3) % d2;
        int cp = e % d3;
        float re = 0.f;
        for (int i = 0; i < d1; ++i) {
            for (int kk = 0; kk < d2; ++kk) {
                int m1 = i - j1, m2 = kk - j2, m3 = m1 + m2;
                if (m3 < -j3 || m3 > j3) continue;
                float cg = su2cgf(j1, m1, j2, m2, j3, m3);
                if (cg == 0.f) continue;
                float q1r, q1i, q2r, q2i, q3r, q3i;
                qelemf(j1, i, a, &q1r, &q1i);
                qelemf(j2, kk, b2, &q2r, &q2i);
                qelemf(j3, j3 + m3, cp, &q3r, &q3i);
                q3i = -q3i;
                float pr = q1r * q2r - q1i * q2i;
                float pi = q1r * q2i + q1i * q2r;
                re += (pr * q3r - pi * q3i) * cg;
            }
        }
        float val = (fabsf(re) < 1e-4f) ? 0.f : re;
        cgws[off + (a * d2 + b2) * d3 + cp] = val;
    }
}

// ---------------------------------------------------------------------------
// kernel B: compact nnz lists per (cg-term, m3) + 972 cg-job records (1 block)
__global__ __launch_bounds__(256) void sh_tab_kernel(const float* __restrict__ cgws,
                                                     int2* __restrict__ lists,
                                                     int4* __restrict__ jobs) {
    __shared__ int cnts[27 * 7];
    int tid = threadIdx.x;
    if (tid < 189) {
        int k = tid / 7, p = tid % 7;
        int t = 0, seen = -1;
        for (t = 0; t < 34; ++t) { if (T_cg[t] >= 0) { ++seen; if (seen == k) break; } }
        int J = T_J[t], j = T_j[t], l = T_l[t];
        int cnt = 0;
        if (p < 2 * J + 1) {
            int base = T_cg[t];
            int dJ = 2 * J + 1, nj = 2 * j + 1, nl = 2 * l + 1;
            int lbase = base + p * nj * nl;
            for (int n = 0; n < nj; ++n)
                for (int m = 0; m < nl; ++m) {
                    float cf = cgws[base + (n * nl + m) * dJ + p];
                    if (cf != 0.f) {
                        // offset in ELEMENT units within reduced Y
                        lists[lbase + cnt] =
                            make_int2(n * (4 - j) * YCOLS + m * 16, __float_as_int(cf));
                        ++cnt;
                    }
                }
        }
        cnts[k * 7 + p] = cnt;
    }
    __syncthreads();
    for (int jid = tid; jid < NJOBS_CG; jid += 256) {
        int t = 0, q = jid, cgIdx = -1;
        for (t = 0; t < 34; ++t) {
            if (T_cg[t] < 0) continue;
            ++cgIdx;
            int npt = (2 * T_J[t] + 1) * (4 - T_j[t]) * 4;
            if (q < npt) break;
            q -= npt;
        }
        int J = T_J[t], j = T_j[t], l = T_l[t];
        int rc = (4 - j) * 4;
        int p = q / rc;
        int rem = q % rc;
        int r = rem >> 2, c4 = rem & 3;
        int out_off = OTAB[J] + p * WTAB[J] + T_ch[t] + r * 16 + c4 * 4;
        int y_base = (YOFFP[j] + r) * YCOLS + (COFF[l] - 16) + c4 * 4;  // element units
        int list_off = T_cg[t] + p * (2 * j + 1) * (2 * l + 1);
        int count = cnts[cgIdx * 7 + p];
        jobs[jid] = make_int4(out_off | (J << 28), y_base, list_off, count);
    }
}

// ---------------------------------------------------------------------------
// MFMA helpers: split-bf16 (hi + residual) fragments, fp32-equivalent GEMM.
static __device__ __forceinline__ s16x8 mkfrag(unsigned d0, unsigned d1,
                                               unsigned d2, unsigned d3) {
    u32x4 t = {d0, d1, d2, d3};
    return __builtin_bit_cast(s16x8, t);
}

// 8 fp32 -> hi-bf16 frag + lo-residual-bf16 frag (truncation split; residual
// captures the rest, dropped lo*lo term is ~2^-16 relative).
static __device__ __forceinline__ void split8(const float* v, s16x8* hi, s16x8* lo) {
    unsigned hd[4], ld[4];
#pragma unroll
    for (int i = 0; i < 4; ++i) {
        unsigned u0 = __float_as_uint(v[2 * i]);
        unsigned u1 = __float_as_uint(v[2 * i + 1]);
        unsigned h0 = u0 & 0xffff0000u;
        unsigned h1 = u1 & 0xffff0000u;
        float l0 = v[2 * i]     - __uint_as_float(h0);
        float l1 = v[2 * i + 1] - __uint_as_float(h1);
        hd[i] = (u0 >> 16) | h1;
        ld[i] = (__float_as_uint(l0) >> 16) | (__float_as_uint(l1) & 0xffff0000u);
    }
    *hi = mkfrag(hd[0], hd[1], hd[2], hd[3]);
    *lo = mkfrag(ld[0], ld[1], ld[2], ld[3]);
}

static __device__ __forceinline__ f32x4 MFMA(s16x8 a, s16x8 b, f32x4 c) {
    return __builtin_amdgcn_mfma_f32_16x16x32_bf16(a, b, c, 0, 0, 0);
}

// ---------------------------------------------------------------------------
// conv kernel: D(256x32) = G^T(256x32) · Kpad(32x32), tiled 16x16x32.
// Tile m covers channels [16m,16m+16); wave w owns m in [4w,4w+4).
// Lane (g=lane>>4, li=lane&15):
//   A frag (G^T): row c = 16m+li, k-slot e -> p = 4g+(e&3) + (e>=4 ? 16 : 0)
//   B frag (Kpad): col r = 16nt+li, same k-slot map (A/B symmetric => any
//                  k bijection is valid as long as both sides use it)
//   D: lane holds channels cb..cb+3 (cb=16m+4g) at y-row r=16nt+li (f32x4).
__global__ __launch_bounds__(256, 6) void sh_conv_kernel(
    const float* __restrict__ x0, const float* __restrict__ x1,
    const float* __restrict__ x2, const float* __restrict__ x3,
    const int* __restrict__ pidx, const float* __restrict__ kern,
    const int2* __restrict__ lists, const int4* __restrict__ jobs,
    float* __restrict__ out) {
    __shared__ __align__(16) float Y[YROWS * YCOLS];  // 25376 B, fp32

    const int bv   = blockIdx.x;
    const int tid  = threadIdx.x;
    const int w    = tid >> 6;
    const int lane = tid & 63;
    const int g    = lane >> 4;
    const int li   = lane & 15;

    const float* kb = kern + (size_t)bv * (NP * NY);
    const int*   pp = pidx + (size_t)bv * (NP * 2);

    // gather row index per k-slot (shared by all 4 tiles of this wave)
    int rows[8];
#pragma unroll
    for (int e = 0; e < 8; ++e) {
        int p = 4 * g + (e & 3) + ((e >= 4) ? 16 : 0);
        int2 pr = ((const int2*)pp)[p];
        rows[e] = pr.x * NN + pr.y;
    }

    // ---- B fragments (Kpad), rows 30/31 zero-padded ----
    s16x8 Bhi[2], Blo[2];
#pragma unroll
    for (int nt = 0; nt < 2; ++nt) {
        int rr = nt * 16 + li;
        float kv[8];
#pragma unroll
        for (int e = 0; e < 8; ++e) {
            int p = 4 * g + (e & 3) + ((e >= 4) ? 16 : 0);
            kv[e] = (rr < NY) ? kb[p * NY + rr] : 0.f;
        }
        split8(kv, &Bhi[nt], &Blo[nt]);
    }

    const int sJ0 = bv * 160, sJ1 = bv * 1008, sJ2 = bv * 1920, sJ3 = bv * 2240;

    // ---- per-tile: gather A, 6 MFMAs (3-way split x 2 nt), fused epilogue ---
#pragma unroll
    for (int m = 0; m < 16; ++m) {
        if ((m >> 2) != w) continue;   // wave-uniform guard (compile-time m)

        const float* src; int strd;
        if (m == 0)     { src = x0 + li;                  strd = 16;  }
        else if (m < 4) { src = x1 + (16 * m + li - 16);  strd = 48;  }
        else if (m < 9) { src = x2 + (16 * m + li - 64);  strd = 80;  }
        else            { src = x3 + (16 * m + li - 144); strd = 112; }

        float gv[8];
#pragma unroll
        for (int e = 0; e < 8; ++e)
            gv[e] = src[(size_t)rows[e] * strd];

        s16x8 Ahi, Alo;
        split8(gv, &Ahi, &Alo);

        f32x4 a0 = {0.f, 0.f, 0.f, 0.f};
        f32x4 a1 = {0.f, 0.f, 0.f, 0.f};
        a0 = MFMA(Ahi, Bhi[0], a0);
        a0 = MFMA(Ahi, Blo[0], a0);
        a0 = MFMA(Alo, Bhi[0], a0);
        a1 = MFMA(Ahi, Bhi[1], a1);
        a1 = MFMA(Ahi, Blo[1], a1);
        a1 = MFMA(Alo, Bhi[1], a1);

        const int cb = 16 * m + 4 * g;   // 4 consecutive channels per lane
#pragma unroll
        for (int nt = 0; nt < 2; ++nt) {
            f32x4 v = nt ? a1 : a0;
            int r = 16 * nt + li;        // y-row
            if (m == 0) {
                // l0 copies: channels 0..15, all 30 rows, fp32 exact-path
                if (r < NY) {
                    int ot, sj, wt, p, rr2;
                    if (r < 4)       { ot = 0;        sj = sJ0; wt = 160; p = 0;      rr2 = r; }
                    else if (r < 13) { int t = r - 4;  ot = 1310720; sj = sJ1; wt = 336;
                                       p = t / 3;  rr2 = t - 3 * (t / 3); }
                    else if (r < 23) { int t = r - 13; ot = 9568256; sj = sJ2; wt = 384;
                                       p = t >> 1; rr2 = t & 1; }
                    else             { ot = 25296896; sj = sJ3; wt = 320; p = r - 23; rr2 = 0; }
                    float* ob = out + (size_t)ot + sj + p * wt + rr2 * 16 + cb;
                    __builtin_nontemporal_store(v, (f32x4*)ob);
                }
            } else {
                if (r < 4) {
                    // j0 copies: rows 0..3, channels >= 16 (class compile-time per m)
                    const int ot = (m < 4) ? 1310720 : (m < 9 ? 9568256 : 25296896);
                    const int wt = (m < 4) ? 336 : (m < 9 ? 384 : 320);
                    const int cj = (m < 4) ? 48  : (m < 9 ? 32  : 16);
                    const int co = (m < 4) ? 16  : (m < 9 ? 64  : 144);
                    const int sj = (m < 4) ? sJ1 : (m < 9 ? sJ2 : sJ3);
                    int rel = cb - co;
                    float* ob = out + (size_t)ot + sj + (rel >> 4) * wt + cj +
                                (rel & 15) + r * 16;
                    __builtin_nontemporal_store(v, (f32x4*)ob);
                } else if (r < NY) {
                    // y rows 4..29, cols 16..255 -> LDS fp32 (one b128 write)
                    *(f32x4*)&Y[(r - 4) * YCOLS + (cb - 16)] = v;
                }
            }
        }
    }

    __syncthreads();

    // ---- cg jobs: one output float4 each, compact nnz list, fp32 y ----------
    for (int jid = tid; jid < NJOBS_CG; jid += 256) {
        int4 jb = jobs[jid];
        int J = ((unsigned)jb.x) >> 28;
        int out_off = jb.x & 0x0FFFFFFF;
        int bvoff = (J < 2) ? (J == 0 ? sJ0 : sJ1) : (J == 2 ? sJ2 : sJ3);
        const int2* lp = lists + jb.z;
        const float* yb = &Y[jb.y];
        f32x4 s = {0.f, 0.f, 0.f, 0.f};
        for (int e = 0; e < jb.w; ++e) {
            int2 en = lp[e];
            float cf = __int_as_float(en.y);
            f32x4 yv = *(const f32x4*)(yb + en.x);   // 16B-aligned by table math
            s.x = fmaf(cf, yv.x, s.x);
            s.y = fmaf(cf, yv.y, s.y);
            s.z = fmaf(cf, yv.z, s.z);
            s.w = fmaf(cf, yv.w, s.w);
        }
        __builtin_nontemporal_store(s, (f32x4*)(out + (size_t)out_off + bvoff));
    }
}

// ---------------------------------------------------------------------------
extern "C" void kernel_launch(void* const* d_in, const int* in_sizes, int n_in,
                              void* d_out, int out_size, void* d_ws, size_t ws_size,
                              hipStream_t stream) {
    const float* x0 = (const float*)d_in[0];
    const float* x1 = (const float*)d_in[1];
    const float* x2 = (const float*)d_in[2];
    const float* x3 = (const float*)d_in[3];
    const int* pidx = (const int*)d_in[4];
    const float* kern = (const float*)d_in[5];

    float* cgws = (float*)d_ws;
    int2* lists = (int2*)((char*)d_ws + LISTS_OFF);
    int4* jobs  = (int4*)((char*)d_ws + JOBS_OFF);

    sh_cg_kernel<<<27, 256, 0, stream>>>(cgws);
    sh_tab_kernel<<<1, 256, 0, stream>>>(cgws, lists, jobs);
    sh_conv_kernel<<<NB * NV, 256, 0, stream>>>(x0, x1, x2, x3, pidx, kern,
                                                lists, jobs, (float*)d_out);
}

// Round 2
// 301.901 us; speedup vs baseline: 1.3992x; 1.2352x over previous
//
#include <hip/hip_runtime.h>
#include <cmath>
#include <cstring>

// ---------------------------------------------------------------------------
// SphericalHarmonicsShellsConv  (MI355X / gfx950) — round 6
//
// Per (b,v):  y(30x256) = K^T(30x32) · G(32x256) gathered  ->  CG recombine.
//
// NEW vs round 5: the CG tables (compact nnz lists + 972 job records) are
// pure compile-time-constant data (~42 KB). They are now computed ONCE on the
// host (double precision, lazy static) and uploaded with a single
// hipMemcpyAsync into d_ws — the two device precompute kernels
// (sh_cg_kernel: divide/sqrt-chain-bound on 27 CUs; sh_tab_kernel: 1-block
// serial) are deleted. Conv kernel is byte-identical to the verified round-5
// version (split-bf16 3-MFMA GEMM, fused epilogue, fp32 LDS Y, CG jobs).
// ---------------------------------------------------------------------------

#define NB      4
#define NN      4096
#define NV      2048
#define NP      32
#define NY      30
#define YROWS   26
#define YCOLS   244          // element row stride (240 cols + 4 pad)
#define NJOBS_CG 972
#define NLISTS   3270
#define JOBS_BYTE_OFF 26160  // 3270*8, 16-aligned (26160 = 16*1635)

typedef float        f32x4 __attribute__((ext_vector_type(4)));
typedef unsigned int u32x4 __attribute__((ext_vector_type(4)));
typedef short        s16x8 __attribute__((ext_vector_type(8)));

// ===========================================================================
// HOST-SIDE table generation (runs once; pure constant data)
// ===========================================================================
namespace shtab {

struct I2 { int x, y; };
struct I4 { int x, y, z, w; };

struct Tabs {
    I2 lists[NLISTS];      // 26160 B
    I4 jobs[NJOBS_CG];     // 15552 B  (starts at byte 26160, 16-aligned)
};
static_assert(sizeof(Tabs) == 26160 + 15552, "layout");

// ---- term tables (34 terms) -----------------------------------------------
static const int T_J[34]  = {0,0,0,0, 1,1,1,1,1,1,1,1,1, 2,2,2,2,2,2,2,2,2,2,2, 3,3,3,3,3,3,3,3,3,3};
static const int T_j[34]  = {0,1,2,3, 1,0,1,2,1,2,3,2,3, 2,0,1,2,3,1,2,3,1,2,3, 3,0,2,3,1,2,3,1,2,3};
static const int T_l[34]  = {0,1,2,3, 0,1,1,1,2,2,2,3,3, 0,2,1,1,1,2,2,2,3,3,3, 0,3,1,1,2,2,2,3,3,3};
static const int T_ch[34] = {0,64,112,144, 0,48,112,160,192,240,272,288,320,
                             0,32,96,144,176,192,240,272,288,336,368,
                             0,16,80,112,128,176,208,224,272,304};
static const int T_cg[34] = {-1,0,9,34, -1,-2,83,110,155,200,275,380,485,
                             -1,-2,632,677,752,857,932,1057,1232,1337,1512,
                             -1,-2,1757,1862,2009,2114,2289,2534,2681,2926};

static const int YOFFP[4] = {0, 0, 9, 19};    // row base in reduced Y (j>=1)
static const int COFF[4]  = {0, 16, 64, 144};
static const int WTAB[4]  = {160, 336, 384, 320};
static const int OTAB[4]  = {0, 1310720, 9568256, 25296896};

static double hfact(int n) {
    static const double F[11] = {1,1,2,6,24,120,720,5040,40320,362880,3628800};
    return F[n];
}

static double h_su2cg(int j1, int m1, int j2, int m2, int j3, int m3) {
    int vmin = -j1 + j2 + m3;
    if (-j1 + m1 > vmin) vmin = -j1 + m1;
    if (0 > vmin) vmin = 0;
    int vmax = j2 + j3 + m1;
    if (j3 - j1 + j2 < vmax) vmax = j3 - j1 + j2;
    if (j3 + m3 < vmax) vmax = j3 + m3;
    double num = (2.0 * j3 + 1.0) * hfact(j3 + j1 - j2) * hfact(j3 - j1 + j2) *
                 hfact(j1 + j2 - j3) * hfact(j3 + m3) * hfact(j3 - m3);
    double den = hfact(j1 + j2 + j3 + 1) * hfact(j1 - m1) * hfact(j1 + m1) *
                 hfact(j2 - m2) * hfact(j2 + m2);
    double C = std::sqrt(num / den);
    double S = 0.0;
    for (int v = vmin; v <= vmax; ++v) {
        double t = hfact(j2 + j3 + m1 - v) * hfact(j1 - m1 + v) /
                   (hfact(v) * hfact(j3 - j1 + j2 - v) * hfact(j3 + m3 - v) *
                    hfact(v + j1 - j2 - m3));
        S += ((v + j2 + m2) & 1) ? -t : t;
    }
    return C * S;
}

// element of (-i)^l * Q_l at (row, col)
static void h_qelem(int l, int row, int col, double* pre, double* pim) {
    int m = row - l;
    const double s2 = 0.70710678118654752440;
    double qr = 0.0, qi = 0.0;
    if (m < 0) {
        if (col == l - m) qr = s2;
        if (col == l + m) qi = -s2;
    } else if (m == 0) {
        if (col == l) qr = 1.0;
    } else {
        double sg = (m & 1) ? -1.0 : 1.0;
        if (col == l + m) qr = sg * s2;
        if (col == l - m) qi = sg * s2;
    }
    double rr, ii;
    switch (l & 3) {
        case 0:  rr = qr;  ii = qi;  break;
        case 1:  rr = qi;  ii = -qr; break;
        case 2:  rr = -qr; ii = -qi; break;
        default: rr = -qi; ii = qr;  break;
    }
    *pre = rr; *pim = ii;
}

static Tabs build_tabs() {
    Tabs T;
    std::memset(&T, 0, sizeof(T));

    static double cgws[3269];
    std::memset(cgws, 0, sizeof(cgws));

    // ---- dense real-CG tables (27 cg terms) -------------------------------
    for (int t = 0; t < 34; ++t) {
        if (T_cg[t] < 0) continue;
        int j1 = T_j[t], j2 = T_l[t], j3 = T_J[t], off = T_cg[t];
        int d1 = 2 * j1 + 1, d2 = 2 * j2 + 1, d3 = 2 * j3 + 1;
        for (int a = 0; a < d1; ++a)
            for (int b2 = 0; b2 < d2; ++b2)
                for (int cp = 0; cp < d3; ++cp) {
                    double re = 0.0;
                    for (int i = 0; i < d1; ++i)
                        for (int kk = 0; kk < d2; ++kk) {
                            int m1 = i - j1, m2 = kk - j2, m3 = m1 + m2;
                            if (m3 < -j3 || m3 > j3) continue;
                            double cg = h_su2cg(j1, m1, j2, m2, j3, m3);
                            if (cg == 0.0) continue;
                            double q1r, q1i, q2r, q2i, q3r, q3i;
                            h_qelem(j1, i, a, &q1r, &q1i);
                            h_qelem(j2, kk, b2, &q2r, &q2i);
                            h_qelem(j3, j3 + m3, cp, &q3r, &q3i);
                            q3i = -q3i;  // conj
                            double pr = q1r * q2r - q1i * q2i;
                            double pi = q1r * q2i + q1i * q2r;
                            re += (pr * q3r - pi * q3i) * cg;
                        }
                    double val = (std::fabs(re) < 1e-4) ? 0.0 : re;
                    cgws[off + (a * d2 + b2) * d3 + cp] = val;
                }
    }

    // ---- compact nnz lists per (cg-term, m3) ------------------------------
    int cnts[27 * 7];
    std::memset(cnts, 0, sizeof(cnts));
    {
        int cgIdx = -1;
        for (int t = 0; t < 34; ++t) {
            if (T_cg[t] < 0) continue;
            ++cgIdx;
            int J = T_J[t], j = T_j[t], l = T_l[t];
            int base = T_cg[t];
            int dJ = 2 * J + 1, nj = 2 * j + 1, nl = 2 * l + 1;
            for (int p = 0; p < dJ; ++p) {
                int lbase = base + p * nj * nl;
                int cnt = 0;
                for (int n = 0; n < nj; ++n)
                    for (int m = 0; m < nl; ++m) {
                        float cf = (float)cgws[base + (n * nl + m) * dJ + p];
                        if (cf != 0.f) {
                            // offset in ELEMENT units within reduced fp32 Y
                            I2 e;
                            e.x = n * (4 - j) * YCOLS + m * 16;
                            std::memcpy(&e.y, &cf, 4);
                            T.lists[lbase + cnt] = e;
                            ++cnt;
                        }
                    }
                cnts[cgIdx * 7 + p] = cnt;
            }
        }
    }

    // ---- 972 cg-job records ----------------------------------------------
    for (int jid = 0; jid < NJOBS_CG; ++jid) {
        int t = 0, q = jid, cgIdx = -1;
        for (t = 0; t < 34; ++t) {
            if (T_cg[t] < 0) continue;
            ++cgIdx;
            int npt = (2 * T_J[t] + 1) * (4 - T_j[t]) * 4;
            if (q < npt) break;
            q -= npt;
        }
        int J = T_J[t], j = T_j[t], l = T_l[t];
        int rc = (4 - j) * 4;
        int p = q / rc;
        int rem = q % rc;
        int r = rem >> 2, c4 = rem & 3;
        int out_off = OTAB[J] + p * WTAB[J] + T_ch[t] + r * 16 + c4 * 4;
        int y_base = (YOFFP[j] + r) * YCOLS + (COFF[l] - 16) + c4 * 4;  // elements
        int list_off = T_cg[t] + p * (2 * j + 1) * (2 * l + 1);
        int count = cnts[cgIdx * 7 + p];
        I4 jb;
        jb.x = out_off | (J << 28);
        jb.y = y_base;
        jb.z = list_off;
        jb.w = count;
        T.jobs[jid] = jb;
    }
    return T;
}

static const Tabs& get_tabs() {
    static Tabs T = build_tabs();   // once per process
    return T;
}

} // namespace shtab

// ===========================================================================
// DEVICE: conv kernel (unchanged from verified round 5)
// ===========================================================================

// MFMA helpers: split-bf16 (hi + residual) fragments, fp32-equivalent GEMM.
static __device__ __forceinline__ s16x8 mkfrag(unsigned d0, unsigned d1,
                                               unsigned d2, unsigned d3) {
    u32x4 t = {d0, d1, d2, d3};
    return __builtin_bit_cast(s16x8, t);
}

// 8 fp32 -> hi-bf16 frag + lo-residual-bf16 frag (truncation split; residual
// captures the rest, dropped lo*lo term is ~2^-16 relative).
static __device__ __forceinline__ void split8(const float* v, s16x8* hi, s16x8* lo) {
    unsigned hd[4], ld[4];
#pragma unroll
    for (int i = 0; i < 4; ++i) {
        unsigned u0 = __float_as_uint(v[2 * i]);
        unsigned u1 = __float_as_uint(v[2 * i + 1]);
        unsigned h0 = u0 & 0xffff0000u;
        unsigned h1 = u1 & 0xffff0000u;
        float l0 = v[2 * i]     - __uint_as_float(h0);
        float l1 = v[2 * i + 1] - __uint_as_float(h1);
        hd[i] = (u0 >> 16) | h1;
        ld[i] = (__float_as_uint(l0) >> 16) | (__float_as_uint(l1) & 0xffff0000u);
    }
    *hi = mkfrag(hd[0], hd[1], hd[2], hd[3]);
    *lo = mkfrag(ld[0], ld[1], ld[2], ld[3]);
}

static __device__ __forceinline__ f32x4 MFMA(s16x8 a, s16x8 b, f32x4 c) {
    return __builtin_amdgcn_mfma_f32_16x16x32_bf16(a, b, c, 0, 0, 0);
}

// conv kernel: D(256x32) = G^T(256x32) · Kpad(32x32), tiled 16x16x32.
// Tile m covers channels [16m,16m+16); wave w owns m in [4w,4w+4).
// Lane (g=lane>>4, li=lane&15):
//   A frag (G^T): row c = 16m+li, k-slot e -> p = 4g+(e&3) + (e>=4 ? 16 : 0)
//   B frag (Kpad): col r = 16nt+li, same k-slot map (A/B symmetric => any
//                  k bijection is valid as long as both sides use it)
//   D: lane holds channels cb..cb+3 (cb=16m+4g) at y-row r=16nt+li (f32x4).
__global__ __launch_bounds__(256, 6) void sh_conv_kernel(
    const float* __restrict__ x0, const float* __restrict__ x1,
    const float* __restrict__ x2, const float* __restrict__ x3,
    const int* __restrict__ pidx, const float* __restrict__ kern,
    const int2* __restrict__ lists, const int4* __restrict__ jobs,
    float* __restrict__ out) {
    __shared__ __align__(16) float Y[YROWS * YCOLS];  // 25376 B, fp32

    const int bv   = blockIdx.x;
    const int tid  = threadIdx.x;
    const int w    = tid >> 6;
    const int lane = tid & 63;
    const int g    = lane >> 4;
    const int li   = lane & 15;

    const float* kb = kern + (size_t)bv * (NP * NY);
    const int*   pp = pidx + (size_t)bv * (NP * 2);

    // gather row index per k-slot (shared by all 4 tiles of this wave)
    int rows[8];
#pragma unroll
    for (int e = 0; e < 8; ++e) {
        int p = 4 * g + (e & 3) + ((e >= 4) ? 16 : 0);
        int2 pr = ((const int2*)pp)[p];
        rows[e] = pr.x * NN + pr.y;
    }

    // ---- B fragments (Kpad), rows 30/31 zero-padded ----
    s16x8 Bhi[2], Blo[2];
#pragma unroll
    for (int nt = 0; nt < 2; ++nt) {
        int rr = nt * 16 + li;
        float kv[8];
#pragma unroll
        for (int e = 0; e < 8; ++e) {
            int p = 4 * g + (e & 3) + ((e >= 4) ? 16 : 0);
            kv[e] = (rr < NY) ? kb[p * NY + rr] : 0.f;
        }
        split8(kv, &Bhi[nt], &Blo[nt]);
    }

    const int sJ0 = bv * 160, sJ1 = bv * 1008, sJ2 = bv * 1920, sJ3 = bv * 2240;

    // ---- per-tile: gather A, 6 MFMAs (3-way split x 2 nt), fused epilogue ---
#pragma unroll
    for (int m = 0; m < 16; ++m) {
        if ((m >> 2) != w) continue;   // wave-uniform guard (compile-time m)

        const float* src; int strd;
        if (m == 0)     { src = x0 + li;                  strd = 16;  }
        else if (m < 4) { src = x1 + (16 * m + li - 16);  strd = 48;  }
        else if (m < 9) { src = x2 + (16 * m + li - 64);  strd = 80;  }
        else            { src = x3 + (16 * m + li - 144); strd = 112; }

        float gv[8];
#pragma unroll
        for (int e = 0; e < 8; ++e)
            gv[e] = src[(size_t)rows[e] * strd];

        s16x8 Ahi, Alo;
        split8(gv, &Ahi, &Alo);

        f32x4 a0 = {0.f, 0.f, 0.f, 0.f};
        f32x4 a1 = {0.f, 0.f, 0.f, 0.f};
        a0 = MFMA(Ahi, Bhi[0], a0);
        a0 = MFMA(Ahi, Blo[0], a0);
        a0 = MFMA(Alo, Bhi[0], a0);
        a1 = MFMA(Ahi, Bhi[1], a1);
        a1 = MFMA(Ahi, Blo[1], a1);
        a1 = MFMA(Alo, Bhi[1], a1);

        const int cb = 16 * m + 4 * g;   // 4 consecutive channels per lane
#pragma unroll
        for (int nt = 0; nt < 2; ++nt) {
            f32x4 v = nt ? a1 : a0;
            int r = 16 * nt + li;        // y-row
            if (m == 0) {
                // l0 copies: channels 0..15, all 30 rows, fp32 exact-path
                if (r < NY) {
                    int ot, sj, wt, p, rr2;
                    if (r < 4)       { ot = 0;        sj = sJ0; wt = 160; p = 0;      rr2 = r; }
                    else if (r < 13) { int t = r - 4;  ot = 1310720; sj = sJ1; wt = 336;
                                       p = t / 3;  rr2 = t - 3 * (t / 3); }
                    else if (r < 23) { int t = r - 13; ot = 9568256; sj = sJ2; wt = 384;
                                       p = t >> 1; rr2 = t & 1; }
                    else             { ot = 25296896; sj = sJ3; wt = 320; p = r - 23; rr2 = 0; }
                    float* ob = out + (size_t)ot + sj + p * wt + rr2 * 16 + cb;
                    __builtin_nontemporal_store(v, (f32x4*)ob);
                }
            } else {
                if (r < 4) {
                    // j0 copies: rows 0..3, channels >= 16 (class compile-time per m)
                    const int ot = (m < 4) ? 1310720 : (m < 9 ? 9568256 : 25296896);
                    const int wt = (m < 4) ? 336 : (m < 9 ? 384 : 320);
                    const int cj = (m < 4) ? 48  : (m < 9 ? 32  : 16);
                    const int co = (m < 4) ? 16  : (m < 9 ? 64  : 144);
                    const int sj = (m < 4) ? sJ1 : (m < 9 ? sJ2 : sJ3);
                    int rel = cb - co;
                    float* ob = out + (size_t)ot + sj + (rel >> 4) * wt + cj +
                                (rel & 15) + r * 16;
                    __builtin_nontemporal_store(v, (f32x4*)ob);
                } else if (r < NY) {
                    // y rows 4..29, cols 16..255 -> LDS fp32 (one b128 write)
                    *(f32x4*)&Y[(r - 4) * YCOLS + (cb - 16)] = v;
                }
            }
        }
    }

    __syncthreads();

    // ---- cg jobs: one output float4 each, compact nnz list, fp32 y ----------
    for (int jid = tid; jid < NJOBS_CG; jid += 256) {
        int4 jb = jobs[jid];
        int J = ((unsigned)jb.x) >> 28;
        int out_off = jb.x & 0x0FFFFFFF;
        int bvoff = (J < 2) ? (J == 0 ? sJ0 : sJ1) : (J == 2 ? sJ2 : sJ3);
        const int2* lp = lists + jb.z;
        const float* yb = &Y[jb.y];
        f32x4 s = {0.f, 0.f, 0.f, 0.f};
        for (int e = 0; e < jb.w; ++e) {
            int2 en = lp[e];
            float cf = __int_as_float(en.y);
            f32x4 yv = *(const f32x4*)(yb + en.x);   // 16B-aligned by table math
            s.x = fmaf(cf, yv.x, s.x);
            s.y = fmaf(cf, yv.y, s.y);
            s.z = fmaf(cf, yv.z, s.z);
            s.w = fmaf(cf, yv.w, s.w);
        }
        __builtin_nontemporal_store(s, (f32x4*)(out + (size_t)out_off + bvoff));
    }
}

// ---------------------------------------------------------------------------
extern "C" void kernel_launch(void* const* d_in, const int* in_sizes, int n_in,
                              void* d_out, int out_size, void* d_ws, size_t ws_size,
                              hipStream_t stream) {
    const float* x0 = (const float*)d_in[0];
    const float* x1 = (const float*)d_in[1];
    const float* x2 = (const float*)d_in[2];
    const float* x3 = (const float*)d_in[3];
    const int* pidx = (const int*)d_in[4];
    const float* kern = (const float*)d_in[5];

    // host-built constant tables -> workspace (single small async copy)
    const shtab::Tabs& T = shtab::get_tabs();
    hipMemcpyAsync(d_ws, &T, sizeof(shtab::Tabs), hipMemcpyHostToDevice, stream);

    const int2* lists = (const int2*)d_ws;
    const int4* jobs  = (const int4*)((const char*)d_ws + JOBS_BYTE_OFF);

    sh_conv_kernel<<<NB * NV, 256, 0, stream>>>(x0, x1, x2, x3, pidx, kern,
                                                lists, jobs, (float*)d_out);
}

// Round 4
// 295.150 us; speedup vs baseline: 1.4313x; 1.0229x over previous
//
#include <hip/hip_runtime.h>
#include <cmath>
#include <cstring>
#include <algorithm>

// ---------------------------------------------------------------------------
// SphericalHarmonicsShellsConv  (MI355X / gfx950) — round 7 (resubmit; round-3
// bench failed with GPUAcquisitionTimeout — no signal, kernel unchanged)
//
// Per (b,v):  y(30x256) = K^T(30x32) · G(32x256) gathered  ->  CG recombine.
//
// NEW vs round 6:
//  * All output stores are plain (not nontemporal): 16B scattered NT stores
//    were causing partial-line HBM writes (WRITE 182 vs 112 MB compulsory)
//    plus RMW fetches (FETCH 81 vs ~50 MB). L2 now merges lines.
//  * CG nnz lists are padded to multiples of 4 entries (zero-coef pads) with
//    16B-aligned bases: inner loop processes 4 entries/iter via two int4
//    list loads + 4 independent ds_read_b128 -> 1/4 the dependent-latency
//    chain length.
//  * Jobs stable-sorted by descending entry count: balanced strided
//    assignment across 256 threads; equal-count c4-siblings stay adjacent
//    so their 16B stores still coalesce to 64B lines.
// ---------------------------------------------------------------------------

#define NB      4
#define NN      4096
#define NV      2048
#define NP      32
#define NY      30
#define YROWS   26
#define YCOLS   244          // element row stride (240 cols + 4 pad)
#define NJOBS_CG 972
#define NLISTS_MAX 4096
#define JOBS_BYTE_OFF 32768  // NLISTS_MAX * 8

typedef float        f32x4 __attribute__((ext_vector_type(4)));
typedef unsigned int u32x4 __attribute__((ext_vector_type(4)));
typedef short        s16x8 __attribute__((ext_vector_type(8)));

// ===========================================================================
// HOST-SIDE table generation (runs once; pure constant data)
// ===========================================================================
namespace shtab {

struct I2 { int x, y; };
struct I4 { int x, y, z, w; };

struct Tabs {
    I2 lists[NLISTS_MAX];  // 32768 B (padded, 4-entry-aligned lists)
    I4 jobs[NJOBS_CG];     // 15552 B  (starts at byte 32768, 16-aligned)
};
static_assert(sizeof(Tabs) == 32768 + 15552, "layout");

// ---- term tables (34 terms) -----------------------------------------------
static const int T_J[34]  = {0,0,0,0, 1,1,1,1,1,1,1,1,1, 2,2,2,2,2,2,2,2,2,2,2, 3,3,3,3,3,3,3,3,3,3};
static const int T_j[34]  = {0,1,2,3, 1,0,1,2,1,2,3,2,3, 2,0,1,2,3,1,2,3,1,2,3, 3,0,2,3,1,2,3,1,2,3};
static const int T_l[34]  = {0,1,2,3, 0,1,1,1,2,2,2,3,3, 0,2,1,1,1,2,2,2,3,3,3, 0,3,1,1,2,2,2,3,3,3};
static const int T_ch[34] = {0,64,112,144, 0,48,112,160,192,240,272,288,320,
                             0,32,96,144,176,192,240,272,288,336,368,
                             0,16,80,112,128,176,208,224,272,304};
static const int T_cg[34] = {-1,0,9,34, -1,-2,83,110,155,200,275,380,485,
                             -1,-2,632,677,752,857,932,1057,1232,1337,1512,
                             -1,-2,1757,1862,2009,2114,2289,2534,2681,2926};

static const int YOFFP[4] = {0, 0, 9, 19};    // row base in reduced Y (j>=1)
static const int COFF[4]  = {0, 16, 64, 144};
static const int WTAB[4]  = {160, 336, 384, 320};
static const int OTAB[4]  = {0, 1310720, 9568256, 25296896};

static double hfact(int n) {
    static const double F[11] = {1,1,2,6,24,120,720,5040,40320,362880,3628800};
    return F[n];
}

static double h_su2cg(int j1, int m1, int j2, int m2, int j3, int m3) {
    int vmin = -j1 + j2 + m3;
    if (-j1 + m1 > vmin) vmin = -j1 + m1;
    if (0 > vmin) vmin = 0;
    int vmax = j2 + j3 + m1;
    if (j3 - j1 + j2 < vmax) vmax = j3 - j1 + j2;
    if (j3 + m3 < vmax) vmax = j3 + m3;
    double num = (2.0 * j3 + 1.0) * hfact(j3 + j1 - j2) * hfact(j3 - j1 + j2) *
                 hfact(j1 + j2 - j3) * hfact(j3 + m3) * hfact(j3 - m3);
    double den = hfact(j1 + j2 + j3 + 1) * hfact(j1 - m1) * hfact(j1 + m1) *
                 hfact(j2 - m2) * hfact(j2 + m2);
    double C = std::sqrt(num / den);
    double S = 0.0;
    for (int v = vmin; v <= vmax; ++v) {
        double t = hfact(j2 + j3 + m1 - v) * hfact(j1 - m1 + v) /
                   (hfact(v) * hfact(j3 - j1 + j2 - v) * hfact(j3 + m3 - v) *
                    hfact(v + j1 - j2 - m3));
        S += ((v + j2 + m2) & 1) ? -t : t;
    }
    return C * S;
}

// element of (-i)^l * Q_l at (row, col)
static void h_qelem(int l, int row, int col, double* pre, double* pim) {
    int m = row - l;
    const double s2 = 0.70710678118654752440;
    double qr = 0.0, qi = 0.0;
    if (m < 0) {
        if (col == l - m) qr = s2;
        if (col == l + m) qi = -s2;
    } else if (m == 0) {
        if (col == l) qr = 1.0;
    } else {
        double sg = (m & 1) ? -1.0 : 1.0;
        if (col == l + m) qr = sg * s2;
        if (col == l - m) qi = sg * s2;
    }
    double rr, ii;
    switch (l & 3) {
        case 0:  rr = qr;  ii = qi;  break;
        case 1:  rr = qi;  ii = -qr; break;
        case 2:  rr = -qr; ii = -qi; break;
        default: rr = -qi; ii = qr;  break;
    }
    *pre = rr; *pim = ii;
}

static Tabs build_tabs() {
    Tabs T;
    std::memset(&T, 0, sizeof(T));

    static double cgws[3269];
    std::memset(cgws, 0, sizeof(cgws));

    // ---- dense real-CG tables (27 cg terms) -------------------------------
    for (int t = 0; t < 34; ++t) {
        if (T_cg[t] < 0) continue;
        int j1 = T_j[t], j2 = T_l[t], j3 = T_J[t], off = T_cg[t];
        int d1 = 2 * j1 + 1, d2 = 2 * j2 + 1, d3 = 2 * j3 + 1;
        for (int a = 0; a < d1; ++a)
            for (int b2 = 0; b2 < d2; ++b2)
                for (int cp = 0; cp < d3; ++cp) {
                    double re = 0.0;
                    for (int i = 0; i < d1; ++i)
                        for (int kk = 0; kk < d2; ++kk) {
                            int m1 = i - j1, m2 = kk - j2, m3 = m1 + m2;
                            if (m3 < -j3 || m3 > j3) continue;
                            double cg = h_su2cg(j1, m1, j2, m2, j3, m3);
                            if (cg == 0.0) continue;
                            double q1r, q1i, q2r, q2i, q3r, q3i;
                            h_qelem(j1, i, a, &q1r, &q1i);
                            h_qelem(j2, kk, b2, &q2r, &q2i);
                            h_qelem(j3, j3 + m3, cp, &q3r, &q3i);
                            q3i = -q3i;  // conj
                            double pr = q1r * q2r - q1i * q2i;
                            double pi = q1r * q2i + q1i * q2r;
                            re += (pr * q3r - pi * q3i) * cg;
                        }
                    double val = (std::fabs(re) < 1e-4) ? 0.0 : re;
                    cgws[off + (a * d2 + b2) * d3 + cp] = val;
                }
    }

    // ---- compact nnz lists, padded to 4-entry multiples, 16B-aligned ------
    int pbase[27 * 7];
    int pcnt[27 * 7];
    std::memset(pbase, 0, sizeof(pbase));
    std::memset(pcnt, 0, sizeof(pcnt));
    int cur = 0;
    {
        int cgIdx = -1;
        for (int t = 0; t < 34; ++t) {
            if (T_cg[t] < 0) continue;
            ++cgIdx;
            int J = T_J[t], j = T_j[t], l = T_l[t];
            int base = T_cg[t];
            int dJ = 2 * J + 1, nj = 2 * j + 1, nl = 2 * l + 1;
            for (int p = 0; p < dJ; ++p) {
                pbase[cgIdx * 7 + p] = cur;
                int cnt = 0;
                for (int n = 0; n < nj; ++n)
                    for (int m = 0; m < nl; ++m) {
                        float cf = (float)cgws[base + (n * nl + m) * dJ + p];
                        if (cf != 0.f) {
                            I2 e;
                            e.x = n * (4 - j) * YCOLS + m * 16;  // element units
                            std::memcpy(&e.y, &cf, 4);
                            T.lists[cur + cnt] = e;
                            ++cnt;
                        }
                    }
                // pad to multiple of 4 with {off=0, coef=0}
                while (cnt & 3) {
                    I2 z; z.x = 0; z.y = 0;
                    T.lists[cur + cnt] = z;
                    ++cnt;
                }
                pcnt[cgIdx * 7 + p] = cnt;
                cur += cnt;
            }
        }
    }
    // cur <= 3269 + 189*3 = 3836 <= NLISTS_MAX

    // ---- 972 cg-job records ----------------------------------------------
    for (int jid = 0; jid < NJOBS_CG; ++jid) {
        int t = 0, q = jid, cgIdx = -1;
        for (t = 0; t < 34; ++t) {
            if (T_cg[t] < 0) continue;
            ++cgIdx;
            int npt = (2 * T_J[t] + 1) * (4 - T_j[t]) * 4;
            if (q < npt) break;
            q -= npt;
        }
        int J = T_J[t], j = T_j[t], l = T_l[t];
        int rc = (4 - j) * 4;
        int p = q / rc;
        int rem = q % rc;
        int r = rem >> 2, c4 = rem & 3;
        int out_off = OTAB[J] + p * WTAB[J] + T_ch[t] + r * 16 + c4 * 4;
        int y_base = (YOFFP[j] + r) * YCOLS + (COFF[l] - 16) + c4 * 4;  // elements
        I4 jb;
        jb.x = out_off | (J << 28);
        jb.y = y_base;
        jb.z = pbase[cgIdx * 7 + p];
        jb.w = pcnt[cgIdx * 7 + p];
        T.jobs[jid] = jb;
    }

    // ---- stable sort by descending count: balances strided assignment,
    //      keeps equal-count c4-siblings adjacent (store coalescing) --------
    std::stable_sort(T.jobs, T.jobs + NJOBS_CG,
                     [](const I4& a, const I4& b) { return a.w > b.w; });
    return T;
}

static const Tabs& get_tabs() {
    static Tabs T = build_tabs();   // once per process
    return T;
}

} // namespace shtab

// ===========================================================================
// DEVICE: conv kernel
// ===========================================================================

// MFMA helpers: split-bf16 (hi + residual) fragments, fp32-equivalent GEMM.
static __device__ __forceinline__ s16x8 mkfrag(unsigned d0, unsigned d1,
                                               unsigned d2, unsigned d3) {
    u32x4 t = {d0, d1, d2, d3};
    return __builtin_bit_cast(s16x8, t);
}

// 8 fp32 -> hi-bf16 frag + lo-residual-bf16 frag (truncation split; residual
// captures the rest, dropped lo*lo term is ~2^-16 relative).
static __device__ __forceinline__ void split8(const float* v, s16x8* hi, s16x8* lo) {
    unsigned hd[4], ld[4];
#pragma unroll
    for (int i = 0; i < 4; ++i) {
        unsigned u0 = __float_as_uint(v[2 * i]);
        unsigned u1 = __float_as_uint(v[2 * i + 1]);
        unsigned h0 = u0 & 0xffff0000u;
        unsigned h1 = u1 & 0xffff0000u;
        float l0 = v[2 * i]     - __uint_as_float(h0);
        float l1 = v[2 * i + 1] - __uint_as_float(h1);
        hd[i] = (u0 >> 16) | h1;
        ld[i] = (__float_as_uint(l0) >> 16) | (__float_as_uint(l1) & 0xffff0000u);
    }
    *hi = mkfrag(hd[0], hd[1], hd[2], hd[3]);
    *lo = mkfrag(ld[0], ld[1], ld[2], ld[3]);
}

static __device__ __forceinline__ f32x4 MFMA(s16x8 a, s16x8 b, f32x4 c) {
    return __builtin_amdgcn_mfma_f32_16x16x32_bf16(a, b, c, 0, 0, 0);
}

// conv kernel: D(256x32) = G^T(256x32) · Kpad(32x32), tiled 16x16x32.
// Tile m covers channels [16m,16m+16); wave w owns m in [4w,4w+4).
// Lane (g=lane>>4, li=lane&15):
//   A frag (G^T): row c = 16m+li, k-slot e -> p = 4g+(e&3) + (e>=4 ? 16 : 0)
//   B frag (Kpad): col r = 16nt+li, same k-slot map (A/B symmetric => any
//                  k bijection is valid as long as both sides use it)
//   D: lane holds channels cb..cb+3 (cb=16m+4g) at y-row r=16nt+li (f32x4).
__global__ __launch_bounds__(256, 6) void sh_conv_kernel(
    const float* __restrict__ x0, const float* __restrict__ x1,
    const float* __restrict__ x2, const float* __restrict__ x3,
    const int* __restrict__ pidx, const float* __restrict__ kern,
    const int2* __restrict__ lists, const int4* __restrict__ jobs,
    float* __restrict__ out) {
    __shared__ __align__(16) float Y[YROWS * YCOLS];  // 25376 B, fp32

    const int bv   = blockIdx.x;
    const int tid  = threadIdx.x;
    const int w    = tid >> 6;
    const int lane = tid & 63;
    const int g    = lane >> 4;
    const int li   = lane & 15;

    const float* kb = kern + (size_t)bv * (NP * NY);
    const int*   pp = pidx + (size_t)bv * (NP * 2);

    // gather row index per k-slot (shared by all 4 tiles of this wave)
    int rows[8];
#pragma unroll
    for (int e = 0; e < 8; ++e) {
        int p = 4 * g + (e & 3) + ((e >= 4) ? 16 : 0);
        int2 pr = ((const int2*)pp)[p];
        rows[e] = pr.x * NN + pr.y;
    }

    // ---- B fragments (Kpad), rows 30/31 zero-padded ----
    s16x8 Bhi[2], Blo[2];
#pragma unroll
    for (int nt = 0; nt < 2; ++nt) {
        int rr = nt * 16 + li;
        float kv[8];
#pragma unroll
        for (int e = 0; e < 8; ++e) {
            int p = 4 * g + (e & 3) + ((e >= 4) ? 16 : 0);
            kv[e] = (rr < NY) ? kb[p * NY + rr] : 0.f;
        }
        split8(kv, &Bhi[nt], &Blo[nt]);
    }

    const int sJ0 = bv * 160, sJ1 = bv * 1008, sJ2 = bv * 1920, sJ3 = bv * 2240;

    // ---- per-tile: gather A, 6 MFMAs (3-way split x 2 nt), fused epilogue ---
#pragma unroll
    for (int m = 0; m < 16; ++m) {
        if ((m >> 2) != w) continue;   // wave-uniform guard (compile-time m)

        const float* src; int strd;
        if (m == 0)     { src = x0 + li;                  strd = 16;  }
        else if (m < 4) { src = x1 + (16 * m + li - 16);  strd = 48;  }
        else if (m < 9) { src = x2 + (16 * m + li - 64);  strd = 80;  }
        else            { src = x3 + (16 * m + li - 144); strd = 112; }

        float gv[8];
#pragma unroll
        for (int e = 0; e < 8; ++e)
            gv[e] = src[(size_t)rows[e] * strd];

        s16x8 Ahi, Alo;
        split8(gv, &Ahi, &Alo);

        f32x4 a0 = {0.f, 0.f, 0.f, 0.f};
        f32x4 a1 = {0.f, 0.f, 0.f, 0.f};
        a0 = MFMA(Ahi, Bhi[0], a0);
        a0 = MFMA(Ahi, Blo[0], a0);
        a0 = MFMA(Alo, Bhi[0], a0);
        a1 = MFMA(Ahi, Bhi[1], a1);
        a1 = MFMA(Ahi, Blo[1], a1);
        a1 = MFMA(Alo, Bhi[1], a1);

        const int cb = 16 * m + 4 * g;   // 4 consecutive channels per lane
#pragma unroll
        for (int nt = 0; nt < 2; ++nt) {
            f32x4 v = nt ? a1 : a0;
            int r = 16 * nt + li;        // y-row
            if (m == 0) {
                // l0 copies: channels 0..15, all 30 rows, fp32 exact-path
                if (r < NY) {
                    int ot, sj, wt, p, rr2;
                    if (r < 4)       { ot = 0;        sj = sJ0; wt = 160; p = 0;      rr2 = r; }
                    else if (r < 13) { int t = r - 4;  ot = 1310720; sj = sJ1; wt = 336;
                                       p = t / 3;  rr2 = t - 3 * (t / 3); }
                    else if (r < 23) { int t = r - 13; ot = 9568256; sj = sJ2; wt = 384;
                                       p = t >> 1; rr2 = t & 1; }
                    else             { ot = 25296896; sj = sJ3; wt = 320; p = r - 23; rr2 = 0; }
                    float* ob = out + (size_t)ot + sj + p * wt + rr2 * 16 + cb;
                    *(f32x4*)ob = v;
                }
            } else {
                if (r < 4) {
                    // j0 copies: rows 0..3, channels >= 16 (class compile-time per m)
                    const int ot = (m < 4) ? 1310720 : (m < 9 ? 9568256 : 25296896);
                    const int wt = (m < 4) ? 336 : (m < 9 ? 384 : 320);
                    const int cj = (m < 4) ? 48  : (m < 9 ? 32  : 16);
                    const int co = (m < 4) ? 16  : (m < 9 ? 64  : 144);
                    const int sj = (m < 4) ? sJ1 : (m < 9 ? sJ2 : sJ3);
                    int rel = cb - co;
                    float* ob = out + (size_t)ot + sj + (rel >> 4) * wt + cj +
                                (rel & 15) + r * 16;
                    *(f32x4*)ob = v;
                } else if (r < NY) {
                    // y rows 4..29, cols 16..255 -> LDS fp32 (one b128 write)
                    *(f32x4*)&Y[(r - 4) * YCOLS + (cb - 16)] = v;
                }
            }
        }
    }

    __syncthreads();

    // ---- cg jobs: one output float4 each; lists padded to 4-entry multiples,
    //      processed 4-wide (2x int4 list loads + 4 independent LDS b128) ----
    for (int jid = tid; jid < NJOBS_CG; jid += 256) {
        int4 jb = jobs[jid];
        int J = ((unsigned)jb.x) >> 28;
        int out_off = jb.x & 0x0FFFFFFF;
        int bvoff = (J < 2) ? (J == 0 ? sJ0 : sJ1) : (J == 2 ? sJ2 : sJ3);
        const int2* lp = lists + jb.z;
        const float* yb = &Y[jb.y];
        f32x4 s = {0.f, 0.f, 0.f, 0.f};
        for (int e = 0; e < jb.w; e += 4) {
            int4 t0 = *(const int4*)(lp + e);       // entries e, e+1
            int4 t1 = *(const int4*)(lp + e + 2);   // entries e+2, e+3
            f32x4 y0 = *(const f32x4*)(yb + t0.x);
            f32x4 y1 = *(const f32x4*)(yb + t0.z);
            f32x4 y2 = *(const f32x4*)(yb + t1.x);
            f32x4 y3 = *(const f32x4*)(yb + t1.z);
            float c0 = __int_as_float(t0.y);
            float c1 = __int_as_float(t0.w);
            float c2 = __int_as_float(t1.y);
            float c3 = __int_as_float(t1.w);
            s.x = fmaf(c0, y0.x, s.x);
            s.y = fmaf(c0, y0.y, s.y);
            s.z = fmaf(c0, y0.z, s.z);
            s.w = fmaf(c0, y0.w, s.w);
            s.x = fmaf(c1, y1.x, s.x);
            s.y = fmaf(c1, y1.y, s.y);
            s.z = fmaf(c1, y1.z, s.z);
            s.w = fmaf(c1, y1.w, s.w);
            s.x = fmaf(c2, y2.x, s.x);
            s.y = fmaf(c2, y2.y, s.y);
            s.z = fmaf(c2, y2.z, s.z);
            s.w = fmaf(c2, y2.w, s.w);
            s.x = fmaf(c3, y3.x, s.x);
            s.y = fmaf(c3, y3.y, s.y);
            s.z = fmaf(c3, y3.z, s.z);
            s.w = fmaf(c3, y3.w, s.w);
        }
        *(f32x4*)(out + (size_t)out_off + bvoff) = s;
    }
}

// ---------------------------------------------------------------------------
extern "C" void kernel_launch(void* const* d_in, const int* in_sizes, int n_in,
                              void* d_out, int out_size, void* d_ws, size_t ws_size,
                              hipStream_t stream) {
    const float* x0 = (const float*)d_in[0];
    const float* x1 = (const float*)d_in[1];
    const float* x2 = (const float*)d_in[2];
    const float* x3 = (const float*)d_in[3];
    const int* pidx = (const int*)d_in[4];
    const float* kern = (const float*)d_in[5];

    // host-built constant tables -> workspace (single small async copy)
    const shtab::Tabs& T = shtab::get_tabs();
    hipMemcpyAsync(d_ws, &T, sizeof(shtab::Tabs), hipMemcpyHostToDevice, stream);

    const int2* lists = (const int2*)d_ws;
    const int4* jobs  = (const int4*)((const char*)d_ws + JOBS_BYTE_OFF);

    sh_conv_kernel<<<NB * NV, 256, 0, stream>>>(x0, x1, x2, x3, pidx, kern,
                                                lists, jobs, (float*)d_out);
}